// Round 11
// baseline (346.695 us; speedup 1.0000x reference)
//
#include <hip/hip_runtime.h>
#include <float.h>

// VQ: B=32, C=64, H=64, W=64, N_EMBED=512
#define C_DIM   64
#define K_CODES 512
#define HW_BITS 12            // HW = 4096
#define N_TOK   131072
#define NW      8             // waves per block; wave w scans codes [64w, 64w+64)
#define KPW     (K_CODES / NW)   // 64 codes per wave

// Prep: transpose embed [C][K] -> eT [K][C], and norms[k] = ||e_k||^2.
__global__ __launch_bounds__(256) void vq_prep(const float* __restrict__ embed,
                                               float* __restrict__ eT,
                                               float* __restrict__ norms) {
    int k = blockIdx.x * blockDim.x + threadIdx.x;
    if (k >= K_CODES) return;
    float s = 0.f;
    #pragma unroll
    for (int c = 0; c < C_DIM; ++c) {
        float v = embed[c * K_CODES + k];   // coalesced across k
        eT[k * C_DIM + c] = v;
        s = fmaf(v, v, s);
    }
    norms[k] = s;
}

// Max-wave config: block = 512 threads = 8 waves over the SAME 64 tokens;
// wave w scans codes [64w, 64w+64) at wave-uniform addresses (s_load path).
// f uses the r3 codegen (plain array, NO pin): compiler keeps ~VGPR<=64 and
// reloads f chunks through the deep-queued L1 vector path -> 8 waves/SIMD
// stack the ~15% per-wave scalar-serialized duty toward the VALU/L1 ceiling.
__global__ __launch_bounds__(512, 8) void vq_main(const float* __restrict__ x,
                                                  const float* __restrict__ eT,
                                                  const float* __restrict__ norms,
                                                  float* __restrict__ out_qwg,
                                                  float* __restrict__ out_q,
                                                  float* __restrict__ out_ind) {
    __shared__ float sS[NW][64];
    __shared__ int   sI[NW][64];
    __shared__ int   gkL[64];

    const int lane = threadIdx.x & 63;
    const int wvu  = __builtin_amdgcn_readfirstlane((int)(threadIdx.x >> 6)); // uniform
    const int tok  = (blockIdx.x << 6) + lane;
    const int b    = tok >> HW_BITS;
    const int hw   = tok & ((1 << HW_BITS) - 1);

    const float* xb = x + ((size_t)b << 18) + hw;   // b*C*HW + hw, per-lane

    float f[C_DIM];
    #pragma unroll
    for (int c = 0; c < C_DIM; ++c) f[c] = xb[(size_t)c << HW_BITS];  // coalesced

    const int    k0    = wvu * KPW;
    const float* eBase = eT + ((size_t)k0 << 6);    // wave-uniform -> s_load path
    const float* nBase = norms + k0;

    float best  = FLT_MAX;
    int   bestk = k0;
    #pragma unroll 2
    for (int kk = 0; kk < KPW; ++kk) {
        const float* e = eBase + (kk << 6);   // uniform -> scalar loads
        float d0 = 0.f, d1 = 0.f, d2 = 0.f, d3 = 0.f;
        #pragma unroll
        for (int c = 0; c < C_DIM; c += 4) {
            d0 = fmaf(f[c + 0], e[c + 0], d0);   // chains = c mod 4, ascending c:
            d1 = fmaf(f[c + 1], e[c + 1], d1);   // bit-identical to rounds 1-10
            d2 = fmaf(f[c + 2], e[c + 2], d2);
            d3 = fmaf(f[c + 3], e[c + 3], d3);
        }
        float dot   = (d0 + d1) + (d2 + d3);
        float score = fmaf(-2.f, dot, nBase[kk]);   // same formula as r1-r10
        if (score < best) { best = score; bestk = k0 + kk; }  // strict < = first min
    }

    sS[wvu][lane] = best;
    sI[wvu][lane] = bestk;
    __syncthreads();

    // merge 8 wave-winners per token (ascending w = ascending code chunks,
    // strict < = global first-min); w0 publishes, writes index output
    if (wvu == 0) {
        float gb = sS[0][lane];
        int   gk = sI[0][lane];
        #pragma unroll
        for (int ww = 1; ww < NW; ++ww) {
            float s = sS[ww][lane];
            if (s < gb) { gb = s; gk = sI[ww][lane]; }
        }
        gkL[lane] = gk;
        out_ind[tok] = (float)gk;
    }
    __syncthreads();

    // epilogue (r5-proven): wave w writes channels [8w, 8w+8) for token = lane.
    // f reloaded from x (L2-hot) to keep all indices compile-time (rule #20).
    {
        const int t  = lane;
        const int gk = gkL[t];
        const int c0 = wvu << 3;
        const float* qr = eT + ((size_t)gk << 6) + c0;     // per-lane gather, L2-hot
        float4 q0 = *(const float4*)(qr);
        float4 q1 = *(const float4*)(qr + 4);

        const int tt = (blockIdx.x << 6) + t;
        const int bb = tt >> HW_BITS;
        const int hh = tt & ((1 << HW_BITS) - 1);
        const float* xr = x + ((size_t)bb << 18) + hh;     // coalesced, L2-hot
        float fv[8];
        #pragma unroll
        for (int j = 0; j < 8; ++j) fv[j] = xr[(size_t)(c0 + j) << HW_BITS];

        float* o0 = out_qwg + ((size_t)bb << 18) + hh;
        float* o1 = out_q   + ((size_t)bb << 18) + hh;

        o0[(size_t)(c0 + 0) << HW_BITS] = fv[0] + (q0.x - fv[0]);
        o0[(size_t)(c0 + 1) << HW_BITS] = fv[1] + (q0.y - fv[1]);
        o0[(size_t)(c0 + 2) << HW_BITS] = fv[2] + (q0.z - fv[2]);
        o0[(size_t)(c0 + 3) << HW_BITS] = fv[3] + (q0.w - fv[3]);
        o0[(size_t)(c0 + 4) << HW_BITS] = fv[4] + (q1.x - fv[4]);
        o0[(size_t)(c0 + 5) << HW_BITS] = fv[5] + (q1.y - fv[5]);
        o0[(size_t)(c0 + 6) << HW_BITS] = fv[6] + (q1.z - fv[6]);
        o0[(size_t)(c0 + 7) << HW_BITS] = fv[7] + (q1.w - fv[7]);

        o1[(size_t)(c0 + 0) << HW_BITS] = q0.x;
        o1[(size_t)(c0 + 1) << HW_BITS] = q0.y;
        o1[(size_t)(c0 + 2) << HW_BITS] = q0.z;
        o1[(size_t)(c0 + 3) << HW_BITS] = q0.w;
        o1[(size_t)(c0 + 4) << HW_BITS] = q1.x;
        o1[(size_t)(c0 + 5) << HW_BITS] = q1.y;
        o1[(size_t)(c0 + 6) << HW_BITS] = q1.z;
        o1[(size_t)(c0 + 7) << HW_BITS] = q1.w;
    }
}

extern "C" void kernel_launch(void* const* d_in, const int* in_sizes, int n_in,
                              void* d_out, int out_size, void* d_ws, size_t ws_size,
                              hipStream_t stream) {
    const float* x     = (const float*)d_in[0];
    const float* embed = (const float*)d_in[1];

    float* out     = (float*)d_out;
    float* out_qwg = out;                       // 8388608 f32
    float* out_q   = out + (size_t)8388608;     // 8388608 f32
    float* out_ind = out + (size_t)16777216;    // 131072 f32

    float* eT    = (float*)d_ws;                // 512*64 f32 = 128 KB
    float* norms = eT + K_CODES * C_DIM;        // 512 f32

    vq_prep<<<2, 256, 0, stream>>>(embed, eT, norms);
    vq_main<<<N_TOK / 64, 512, 0, stream>>>(x, eT, norms, out_qwg, out_q, out_ind);
}